// Round 1
// baseline (1257.077 us; speedup 1.0000x reference)
//
#include <hip/hip_runtime.h>
#include <hip/hip_bf16.h>

typedef unsigned short u16;
typedef __attribute__((ext_vector_type(8))) short bf16x8;
typedef __attribute__((ext_vector_type(8))) unsigned short u16x8;
typedef __attribute__((ext_vector_type(4))) float f32x4;

#define BB 16384
#define DD 2048
#define KEXT 2080   // 2048 x-cols + 16 ss cols + 16 zero pad
#define HH 1024
#define EE 16
#define TOPN 409

__device__ __forceinline__ u16 f2bf(float f) {
    union { float f; unsigned u; } c; c.f = f;
    unsigned r = c.u + 0x7fffu + ((c.u >> 16) & 1u);
    return (u16)(r >> 16);
}
__device__ __forceinline__ float bf2f(u16 h) {
    union { unsigned u; float f; } c; c.u = ((unsigned)h) << 16; return c.f;
}

__device__ __forceinline__ void ld16_lds(const void* g, void* l) {
    __builtin_amdgcn_global_load_lds(
        (const __attribute__((address_space(1))) unsigned int*)g,
        (__attribute__((address_space(3))) unsigned int*)l, 16, 0, 0);
}

// ---------------- prep: transpose/split weights to bf16 ----------------
__global__ __launch_bounds__(256)
void prep_w(const float* __restrict__ Ws1, const float* __restrict__ Wr1,
            const float* __restrict__ Ws2, const float* __restrict__ Wr2,
            const float* __restrict__ pat,
            u16* __restrict__ w1t, u16* __restrict__ wr1h, u16* __restrict__ wr1l,
            u16* __restrict__ w2t1, u16* __restrict__ wr2th, u16* __restrict__ wr2tl,
            u16* __restrict__ patTh, u16* __restrict__ patTl)
{
    int idx = blockIdx.x * 256 + threadIdx.x;
    if (idx < HH * KEXT) {
        int n = idx / KEXT, k = idx % KEXT;
        float v1 = (k < DD) ? Ws1[(size_t)k * HH + n] : 0.0f;
        w1t[idx] = f2bf(v1);
        float v2 = (k < DD + EE) ? Wr1[(size_t)k * HH + n] : 0.0f;
        u16 h = f2bf(v2);
        wr1h[idx] = h;
        wr1l[idx] = f2bf(v2 - bf2f(h));
    }
    if (idx < EE * HH) {
        int e = idx / HH, n = idx % HH;
        w2t1[idx] = f2bf(Ws2[(size_t)n * EE + e]);
        float v = Wr2[(size_t)n * EE + e];
        u16 h = f2bf(v);
        wr2th[idx] = h;
        wr2tl[idx] = f2bf(v - bf2f(h));
    }
    if (idx < EE * DD) {
        float v = pat[idx];   // pat is [E][D] row-major, already transposed layout
        u16 h = f2bf(v);
        patTh[idx] = h;
        patTl[idx] = f2bf(v - bf2f(h));
    }
}

// ---------------- stats + x split-convert + k-predictor ----------------
__global__ __launch_bounds__(256)
void stats_kernel(const float* __restrict__ x,
                  const float* __restrict__ Wk1, const float* __restrict__ bk1,
                  const float* __restrict__ Wk2, const float* __restrict__ bk2,
                  float* __restrict__ stats_out, u16* __restrict__ xh, u16* __restrict__ xl,
                  int* __restrict__ counters)
{
    const int row = blockIdx.x;
    const int t = threadIdx.x;
    const int wid = t >> 6;
    const int lane = t & 63;

    float v[8];
    {
        const float4* xr = (const float4*)(x + (size_t)row * DD + t * 8);
        float4 a = xr[0], b = xr[1];
        v[0]=a.x; v[1]=a.y; v[2]=a.z; v[3]=a.w;
        v[4]=b.x; v[5]=b.y; v[6]=b.z; v[7]=b.w;
    }
    {
        union { u16 a[8]; u16x8 vec; } H, L;
        #pragma unroll
        for (int j = 0; j < 8; ++j) {
            u16 h = f2bf(v[j]); H.a[j] = h; L.a[j] = f2bf(v[j] - bf2f(h));
        }
        *(u16x8*)(xh + (size_t)row * KEXT + t * 8) = H.vec;
        *(u16x8*)(xl + (size_t)row * KEXT + t * 8) = L.vec;
    }

    __shared__ float red[4][8];
    __shared__ float bc[8];

    // pass 1: sum -> mean
    float s = ((v[0]+v[1])+(v[2]+v[3]))+((v[4]+v[5])+(v[6]+v[7]));
    #pragma unroll
    for (int off = 32; off >= 1; off >>= 1) s += __shfl_down(s, off);
    if (lane == 0) red[wid][0] = s;
    __syncthreads();
    if (t == 0) bc[0] = red[0][0]+red[1][0]+red[2][0]+red[3][0];
    __syncthreads();
    const float mean = bc[0] * (1.0f/2048.0f);

    // pass 2: centered moments, abs-sum, sq-sum, max, zero count
    float s2=0, s3=0, sa=0, sq=0, zc=0, mx=0;
    #pragma unroll
    for (int j = 0; j < 8; ++j) {
        float d = v[j] - mean;
        s2 += d*d; s3 += d*d*d;
        float av = fabsf(v[j]);
        sa += av; sq += v[j]*v[j];
        mx = fmaxf(mx, av);
        zc += (v[j] == 0.0f) ? 1.0f : 0.0f;
    }
    #pragma unroll
    for (int off = 32; off >= 1; off >>= 1) {
        s2 += __shfl_down(s2, off);
        s3 += __shfl_down(s3, off);
        sa += __shfl_down(sa, off);
        sq += __shfl_down(sq, off);
        zc += __shfl_down(zc, off);
        mx = fmaxf(mx, __shfl_down(mx, off));
    }
    if (lane == 0) {
        red[wid][0]=s2; red[wid][1]=s3; red[wid][2]=sa;
        red[wid][3]=sq; red[wid][4]=zc; red[wid][5]=mx;
    }
    __syncthreads();
    if (t == 0) {
        bc[0]=red[0][0]+red[1][0]+red[2][0]+red[3][0];
        bc[1]=red[0][1]+red[1][1]+red[2][1]+red[3][1];
        bc[2]=red[0][2]+red[1][2]+red[2][2]+red[3][2];
        bc[3]=red[0][3]+red[1][3]+red[2][3]+red[3][3];
        bc[4]=red[0][4]+red[1][4]+red[2][4]+red[3][4];
        bc[5]=fmaxf(fmaxf(red[0][5],red[1][5]),fmaxf(red[2][5],red[3][5]));
    }
    __syncthreads();
    const float sum2c=bc[0], sum3c=bc[1], sumabs=bc[2], sumsq=bc[3], zeros=bc[4], maxabs=bc[5];

    // exact radix select: T = 409th largest |x|
    unsigned bits[8];
    #pragma unroll
    for (int j = 0; j < 8; ++j) bits[j] = __float_as_uint(fabsf(v[j]));

    __shared__ unsigned hist[256];
    __shared__ unsigned sfx[256];
    __shared__ unsigned selb[2];
    unsigned want = TOPN;
    unsigned prefix = 0;
    for (int p = 3; p >= 0; --p) {
        unsigned maskHi = (p == 3) ? 0u : (0xFFFFFFFFu << (8*(p+1)));
        hist[t] = 0;
        __syncthreads();
        #pragma unroll
        for (int j = 0; j < 8; ++j) {
            if ((bits[j] & maskHi) == prefix)
                atomicAdd(&hist[(bits[j] >> (8*p)) & 255u], 1u);
        }
        __syncthreads();
        sfx[t] = hist[t];
        __syncthreads();
        for (int off = 1; off < 256; off <<= 1) {
            unsigned add = (t + off < 256) ? sfx[t + off] : 0u;
            __syncthreads();
            sfx[t] += add;
            __syncthreads();
        }
        unsigned nxt = (t < 255) ? sfx[t + 1] : 0u;
        if (sfx[t] >= want && nxt < want) { selb[0] = (unsigned)t; selb[1] = want - nxt; }
        __syncthreads();
        prefix |= selb[0] << (8*p);
        want = selb[1];
        __syncthreads();
    }
    const float T = __uint_as_float(prefix);

    float cg = 0, sg = 0;
    #pragma unroll
    for (int j = 0; j < 8; ++j) {
        if (bits[j] > prefix) { cg += 1.0f; sg += __uint_as_float(bits[j]); }
    }
    #pragma unroll
    for (int off = 32; off >= 1; off >>= 1) { cg += __shfl_down(cg, off); sg += __shfl_down(sg, off); }
    if (lane == 0) { red[wid][6] = cg; red[wid][7] = sg; }
    __syncthreads();

    if (t == 0) {
        float cgt = red[0][6]+red[1][6]+red[2][6]+red[3][6];
        float sgt = red[0][7]+red[1][7]+red[2][7]+red[3][7];
        float top = sgt + ((float)TOPN - cgt) * T;
        float var_u = sum2c * (1.0f/2047.0f);
        float stdv = sqrtf(var_u + 1e-8f);
        float st0 = zeros * (1.0f/2048.0f);
        float st1 = var_u;
        float st2 = maxabs;
        float st3 = sqrtf(sumsq);
        float st4 = (sum3c * (1.0f/2048.0f)) / (stdv*stdv*stdv);
        float st5 = top / (sumabs + 1e-8f);
        float* so = stats_out + (size_t)row * 6;
        so[0]=st0; so[1]=st1; so[2]=st2; so[3]=st3; so[4]=st4; so[5]=st5;
        // k predictor MLP (6->16->1) + sigmoid
        float stv[6] = {st0,st1,st2,st3,st4,st5};
        float o = bk2[0];
        #pragma unroll
        for (int i = 0; i < 16; ++i) {
            float h = bk1[i];
            #pragma unroll
            for (int f = 0; f < 6; ++f) h += stv[f] * Wk1[f*16 + i];
            o += fmaxf(h, 0.0f) * Wk2[i];
        }
        float kr = 1.0f / (1.0f + expf(-o));
        float kv = 1.0f + 3.0f * kr;
        if (kv < 2.0f) atomicAdd(&counters[0], 1);
        if (kv < 3.0f) atomicAdd(&counters[1], 1);
    }
}

// ---------------- big GEMM: O = relu(A@B^T + bias), multi-phase split-bf16 ----------------
// A: [16384][astride] bf16 rows; B: [1024][bstride] bf16 rows (pre-transposed: row n holds k)
// out: bf16 hi (and lo if SPLIT) [16384][1024]
template<int NPH, bool SPLIT>
__global__ __launch_bounds__(256)
void gemm_tile(const u16* __restrict__ A0, const u16* __restrict__ B0,
               const u16* __restrict__ A1, const u16* __restrict__ B1,
               const u16* __restrict__ A2, const u16* __restrict__ B2,
               const float* __restrict__ bias,
               u16* __restrict__ Oh, u16* __restrict__ Ol,
               int kiters, int astride, int bstride)
{
    __shared__ u16 As[128*32];
    __shared__ u16 Bs[128*32];
    const int t = threadIdx.x;
    const int m0 = blockIdx.y * 128;
    const int n0 = blockIdx.x * 128;
    const int wid = t >> 6, lane = t & 63, l16 = lane & 15, q = lane >> 4;
    const int wm = (wid & 1) * 64, wn = (wid >> 1) * 64;

    f32x4 acc[4][4] = {};
    const u16* APh[3] = {A0, A1, A2};
    const u16* BPh[3] = {B0, B1, B2};

    const int rowA = t >> 1;            // seg t: rows 0..127, 2 16B chunks per row pair
    for (int ph = 0; ph < NPH; ++ph) {
        const u16* A = APh[ph];
        const u16* B = BPh[ph];
        for (int it = 0; it < kiters; ++it) {
            const int k0 = it * 32;
            __syncthreads();
            #pragma unroll
            for (int s = 0; s < 2; ++s) {
                int seg = t + s * 256;
                int row = seg >> 2;
                int kq = (seg & 3) * 8;
                ld16_lds(A + (size_t)(m0 + row) * astride + k0 + kq, (void*)(As + seg * 8));
                ld16_lds(B + (size_t)(n0 + row) * bstride + k0 + kq, (void*)(Bs + seg * 8));
            }
            __syncthreads();
            bf16x8 af[4], bfr[4];
            #pragma unroll
            for (int i = 0; i < 4; ++i) af[i] = *(const bf16x8*)(As + (wm + 16*i + l16) * 32 + q * 8);
            #pragma unroll
            for (int j = 0; j < 4; ++j) bfr[j] = *(const bf16x8*)(Bs + (wn + 16*j + l16) * 32 + q * 8);
            #pragma unroll
            for (int i = 0; i < 4; ++i)
                #pragma unroll
                for (int j = 0; j < 4; ++j)
                    acc[i][j] = __builtin_amdgcn_mfma_f32_16x16x32_bf16(af[i], bfr[j], acc[i][j], 0, 0, 0);
        }
    }
    (void)rowA;
    // epilogue: bias + relu + (split) bf16 store
    #pragma unroll
    for (int j = 0; j < 4; ++j) {
        int col = n0 + wn + 16*j + l16;
        float bv = bias[col];
        #pragma unroll
        for (int i = 0; i < 4; ++i) {
            #pragma unroll
            for (int r = 0; r < 4; ++r) {
                int row = m0 + wm + 16*i + q*4 + r;
                float vv = acc[i][j][r] + bv;
                vv = vv > 0.0f ? vv : 0.0f;
                u16 h = f2bf(vv);
                Oh[(size_t)row * HH + col] = h;
                if (SPLIT) Ol[(size_t)row * HH + col] = f2bf(vv - bf2f(h));
            }
        }
    }
}

// ---------------- thin GEMM: Out[m][16] = sum_ph A_ph @ B_ph^T (f32 out, no bias) ----------------
template<int NPH>
__global__ __launch_bounds__(256)
void thin_gemm(const u16* __restrict__ A0, const u16* __restrict__ B0,
               const u16* __restrict__ A1, const u16* __restrict__ B1,
               const u16* __restrict__ A2, const u16* __restrict__ B2,
               float* __restrict__ Out, int kiters, int astride, int bstride)
{
    const int t = threadIdx.x;
    const int wid = t >> 6, lane = t & 63, l16 = lane & 15, q = lane >> 4;
    const int m0 = (blockIdx.x * 4 + wid) * 16;
    f32x4 acc = {};
    const u16* APh[3] = {A0, A1, A2};
    const u16* BPh[3] = {B0, B1, B2};
    for (int ph = 0; ph < NPH; ++ph) {
        const u16* A = APh[ph];
        const u16* B = BPh[ph];
        for (int it = 0; it < kiters; ++it) {
            int k0 = it * 32;
            bf16x8 af = *(const bf16x8*)(A + (size_t)(m0 + l16) * astride + k0 + q*8);
            bf16x8 bfr = *(const bf16x8*)(B + (size_t)l16 * bstride + k0 + q*8);
            acc = __builtin_amdgcn_mfma_f32_16x16x32_bf16(af, bfr, acc, 0, 0, 0);
        }
    }
    #pragma unroll
    for (int r = 0; r < 4; ++r) {
        int row = m0 + q*4 + r;
        Out[(size_t)row * EE + l16] = acc[r];
    }
}

// ---------------- spec_scores -> ss columns of xh/xl ----------------
__global__ __launch_bounds__(256)
void ss_kernel(const float* __restrict__ sims, const float* __restrict__ spec,
               const float* __restrict__ bs2,
               u16* __restrict__ xh, u16* __restrict__ xl)
{
    int row = blockIdx.x * 256 + threadIdx.x;
    union { u16 a[8]; u16x8 vec; } H0, H1, L0, L1;
    #pragma unroll
    for (int e = 0; e < 16; ++e) {
        float sarg = sims[(size_t)row*EE + e] + spec[(size_t)row*EE + e] + bs2[e];
        float ssv = 1.0f / (1.0f + expf(-sarg));
        u16 h = f2bf(ssv);
        u16 lo = f2bf(ssv - bf2f(h));
        if (e < 8) { H0.a[e] = h; L0.a[e] = lo; } else { H1.a[e-8] = h; L1.a[e-8] = lo; }
    }
    u16x8 z = {0,0,0,0,0,0,0,0};
    u16* ph = xh + (size_t)row * KEXT + DD;
    u16* pl = xl + (size_t)row * KEXT + DD;
    *(u16x8*)(ph)      = H0.vec;
    *(u16x8*)(ph + 8)  = H1.vec;
    *(u16x8*)(ph + 16) = z;
    *(u16x8*)(ph + 24) = z;
    *(u16x8*)(pl)      = L0.vec;
    *(u16x8*)(pl + 8)  = L1.vec;
    *(u16x8*)(pl + 16) = z;
    *(u16x8*)(pl + 24) = z;
}

// ---------------- final: softmax, top-4, k from median counters, gates ----------------
__global__ __launch_bounds__(256)
void final_kernel(const float* __restrict__ logits, const float* __restrict__ br2,
                  const int* __restrict__ counters,
                  float* __restrict__ out_gates, float* __restrict__ out_idx,
                  float* __restrict__ out_probs)
{
    int row = blockIdx.x * 256 + threadIdx.x;
    float lg[16];
    float m = -1e30f;
    #pragma unroll
    for (int e = 0; e < 16; ++e) {
        lg[e] = logits[(size_t)row*EE + e] + br2[e];
        m = fmaxf(m, lg[e]);
    }
    float p[16], den = 0.0f;
    #pragma unroll
    for (int e = 0; e < 16; ++e) { p[e] = expf(lg[e] - m); den += p[e]; }
    float inv = 1.0f / den;
    #pragma unroll
    for (int e = 0; e < 16; ++e) { p[e] *= inv; out_probs[(size_t)row*EE + e] = p[e]; }

    float tv[4]; int ti[4];
    unsigned used = 0;
    #pragma unroll
    for (int s = 0; s < 4; ++s) {
        float best = -1e30f; int bi = 0;
        #pragma unroll
        for (int e = 0; e < 16; ++e) {
            if (!((used >> e) & 1u) && p[e] > best) { best = p[e]; bi = e; }
        }
        used |= 1u << bi;
        tv[s] = best; ti[s] = bi;
    }
    int c2 = counters[0], c3 = counters[1];
    int k = (c2 >= 8192) ? 1 : ((c3 >= 8192) ? 2 : 3);
    float g[4] = {0,0,0,0};
    float d2 = 0.0f;
    for (int s = 0; s < k; ++s) { g[s] = expf(tv[s] - tv[0]); d2 += g[s]; }
    float i2 = 1.0f / d2;
    #pragma unroll
    for (int s = 0; s < 4; ++s) {
        out_gates[(size_t)row*4 + s] = (s < k) ? g[s] * i2 : 0.0f;
        out_idx[(size_t)row*4 + s] = (float)ti[s];
    }
}

// ---------------- host launch ----------------
extern "C" void kernel_launch(void* const* d_in, const int* in_sizes, int n_in,
                              void* d_out, int out_size, void* d_ws, size_t ws_size,
                              hipStream_t stream) {
    const float* x   = (const float*)d_in[0];
    const float* pat = (const float*)d_in[1];
    const float* Ws1 = (const float*)d_in[2];
    const float* bs1 = (const float*)d_in[3];
    const float* Ws2 = (const float*)d_in[4];
    const float* bs2 = (const float*)d_in[5];
    const float* Wr1 = (const float*)d_in[6];
    const float* br1 = (const float*)d_in[7];
    const float* Wr2 = (const float*)d_in[8];
    const float* br2 = (const float*)d_in[9];
    const float* Wk1 = (const float*)d_in[10];
    const float* bk1 = (const float*)d_in[11];
    const float* Wk2 = (const float*)d_in[12];
    const float* bk2 = (const float*)d_in[13];

    char* ws = (char*)d_ws;
    size_t off = 0;
    auto alloc = [&](size_t bytes) { char* p = ws + off; off += (bytes + 255) & ~(size_t)255; return p; };
    u16* xh     = (u16*)alloc((size_t)BB * KEXT * 2);
    u16* xl     = (u16*)alloc((size_t)BB * KEXT * 2);
    u16* w1t    = (u16*)alloc((size_t)HH * KEXT * 2);
    u16* wr1h   = (u16*)alloc((size_t)HH * KEXT * 2);
    u16* wr1l   = (u16*)alloc((size_t)HH * KEXT * 2);
    u16* w2t1   = (u16*)alloc((size_t)EE * HH * 2);
    u16* wr2th  = (u16*)alloc((size_t)EE * HH * 2);
    u16* wr2tl  = (u16*)alloc((size_t)EE * HH * 2);
    u16* patTh  = (u16*)alloc((size_t)EE * DD * 2);
    u16* patTl  = (u16*)alloc((size_t)EE * DD * 2);
    u16* ha     = (u16*)alloc((size_t)BB * HH * 2);
    u16* hb     = (u16*)alloc((size_t)BB * HH * 2);
    float* sims   = (float*)alloc((size_t)BB * EE * 4);
    float* spec   = (float*)alloc((size_t)BB * EE * 4);
    float* logits = (float*)alloc((size_t)BB * EE * 4);
    int* cnt      = (int*)alloc(64);

    float* out        = (float*)d_out;
    float* out_gates  = out;
    float* out_idx    = out + (size_t)BB * 4;
    float* out_probs  = out + (size_t)BB * 8;
    float* out_stats  = out + (size_t)BB * 24;

    hipMemsetAsync(cnt, 0, 64, stream);

    prep_w<<<(HH*KEXT + 255)/256, 256, 0, stream>>>(Ws1, Wr1, Ws2, Wr2, pat,
        w1t, wr1h, wr1l, w2t1, wr2th, wr2tl, patTh, patTl);

    stats_kernel<<<BB, 256, 0, stream>>>(x, Wk1, bk1, Wk2, bk2, out_stats, xh, xl, cnt);

    // h1 = relu(x@Ws1 + bs1)  (plain bf16 is enough: feeds logits only via sigmoid'd spec)
    gemm_tile<1, false><<<dim3(8, 128), 256, 0, stream>>>(
        xh, w1t, nullptr, nullptr, nullptr, nullptr, bs1, ha, nullptr, 64, KEXT, KEXT);

    // sims = x @ patterns^T  (split 3-term: sims has |values|~45 entering sigmoid)
    thin_gemm<3><<<BB/64, 256, 0, stream>>>(xh, patTh, xh, patTl, xl, patTh, sims, 64, KEXT, DD);

    // spec = h1 @ Ws2
    thin_gemm<1><<<BB/64, 256, 0, stream>>>(ha, w2t1, nullptr, nullptr, nullptr, nullptr, spec, 32, HH, HH);

    // ss = sigmoid(sims + spec + bs2) -> split bf16 into x_ext columns 2048..2079
    ss_kernel<<<BB/256, 256, 0, stream>>>(sims, spec, bs2, xh, xl);

    // h2 = relu(ri@Wr1 + br1), split 3-term, split-bf16 output
    gemm_tile<3, true><<<dim3(8, 128), 256, 0, stream>>>(
        xh, wr1h, xh, wr1l, xl, wr1h, br1, ha, hb, 65, KEXT, KEXT);

    // logits = h2 @ Wr2 (split 3-term)
    thin_gemm<3><<<BB/64, 256, 0, stream>>>(ha, wr2th, ha, wr2tl, hb, wr2th, logits, 32, HH, HH);

    final_kernel<<<BB/256, 256, 0, stream>>>(logits, br2, cnt, out_gates, out_idx, out_probs);
}

// Round 2
// 935.486 us; speedup vs baseline: 1.3438x; 1.3438x over previous
//
#include <hip/hip_runtime.h>
#include <hip/hip_bf16.h>

typedef unsigned short u16;
typedef __attribute__((ext_vector_type(8))) short bf16x8;
typedef __attribute__((ext_vector_type(8))) unsigned short u16x8;
typedef __attribute__((ext_vector_type(4))) float f32x4;

#define BB 16384
#define DD 2048
#define KEXT 2080   // 2048 x-cols + 16 ss cols + 16 zero pad
#define HH 1024
#define EE 16
#define TOPN 409

__device__ __forceinline__ u16 f2bf(float f) {
    union { float f; unsigned u; } c; c.f = f;
    unsigned r = c.u + 0x7fffu + ((c.u >> 16) & 1u);
    return (u16)(r >> 16);
}
__device__ __forceinline__ float bf2f(u16 h) {
    union { unsigned u; float f; } c; c.u = ((unsigned)h) << 16; return c.f;
}

__device__ __forceinline__ void ld16_lds(const void* g, void* l) {
    __builtin_amdgcn_global_load_lds(
        (const __attribute__((address_space(1))) unsigned int*)g,
        (__attribute__((address_space(3))) unsigned int*)l, 16, 0, 0);
}

// ---------------- prep: transpose/split weights to bf16 ----------------
__global__ __launch_bounds__(256)
void prep_w(const float* __restrict__ Ws1, const float* __restrict__ Wr1,
            const float* __restrict__ Ws2, const float* __restrict__ Wr2,
            const float* __restrict__ pat,
            u16* __restrict__ w1t, u16* __restrict__ wr1h, u16* __restrict__ wr1l,
            u16* __restrict__ w2t1, u16* __restrict__ wr2th, u16* __restrict__ wr2tl,
            u16* __restrict__ patTh, u16* __restrict__ patTl)
{
    int idx = blockIdx.x * 256 + threadIdx.x;
    if (idx < HH * KEXT) {
        int n = idx / KEXT, k = idx % KEXT;
        float v1 = (k < DD) ? Ws1[(size_t)k * HH + n] : 0.0f;
        w1t[idx] = f2bf(v1);
        float v2 = (k < DD + EE) ? Wr1[(size_t)k * HH + n] : 0.0f;
        u16 h = f2bf(v2);
        wr1h[idx] = h;
        wr1l[idx] = f2bf(v2 - bf2f(h));
    }
    if (idx < EE * HH) {
        int e = idx / HH, n = idx % HH;
        w2t1[idx] = f2bf(Ws2[(size_t)n * EE + e]);
        float v = Wr2[(size_t)n * EE + e];
        u16 h = f2bf(v);
        wr2th[idx] = h;
        wr2tl[idx] = f2bf(v - bf2f(h));
    }
    if (idx < EE * DD) {
        float v = pat[idx];   // pat is [E][D] row-major, already transposed layout
        u16 h = f2bf(v);
        patTh[idx] = h;
        patTl[idx] = f2bf(v - bf2f(h));
    }
}

// ---------------- stats: 1 wave per row, register-resident, no LDS/atomics ----------------
__global__ __launch_bounds__(256)
void stats_kernel(const float* __restrict__ x,
                  const float* __restrict__ Wk1, const float* __restrict__ bk1,
                  const float* __restrict__ Wk2, const float* __restrict__ bk2,
                  float* __restrict__ stats_out, u16* __restrict__ xh, u16* __restrict__ xl,
                  unsigned* __restrict__ kflags)
{
    const int wid = threadIdx.x >> 6;
    const int lane = threadIdx.x & 63;
    const int row = blockIdx.x * 4 + wid;
    const float* xr = x + (size_t)row * DD;

    // v[s*4+c] = x[row, s*256 + lane*4 + c]  (each load: 64 lanes x 16B = 1KB contiguous)
    float v[32];
    #pragma unroll
    for (int s = 0; s < 8; ++s) {
        float4 a = *(const float4*)(xr + s * 256 + lane * 4);
        v[s*4+0]=a.x; v[s*4+1]=a.y; v[s*4+2]=a.z; v[s*4+3]=a.w;
    }

    // split-bf16 conversion + store (8B per store, 512B/instr coalesced)
    u16* ph = xh + (size_t)row * KEXT;
    u16* pl = xl + (size_t)row * KEXT;
    #pragma unroll
    for (int s = 0; s < 8; ++s) {
        union { u16 a[4]; unsigned long long q; } H, L;
        #pragma unroll
        for (int c = 0; c < 4; ++c) {
            float f = v[s*4+c];
            u16 h = f2bf(f);
            H.a[c] = h; L.a[c] = f2bf(f - bf2f(h));
        }
        *(unsigned long long*)(ph + s*256 + lane*4) = H.q;
        *(unsigned long long*)(pl + s*256 + lane*4) = L.q;
    }

    // pass 1: mean
    float s1 = 0;
    #pragma unroll
    for (int j = 0; j < 32; ++j) s1 += v[j];
    #pragma unroll
    for (int off = 32; off >= 1; off >>= 1) s1 += __shfl_xor(s1, off);
    const float mean = s1 * (1.0f/2048.0f);

    // pass 2: moments
    float s2=0, s3=0, sa=0, sq=0, zc=0, mx=0;
    #pragma unroll
    for (int j = 0; j < 32; ++j) {
        float d = v[j] - mean;
        s2 += d*d; s3 += d*d*d;
        float av = fabsf(v[j]);
        sa += av; sq += v[j]*v[j];
        mx = fmaxf(mx, av);
        zc += (v[j] == 0.0f) ? 1.0f : 0.0f;
    }
    #pragma unroll
    for (int off = 32; off >= 1; off >>= 1) {
        s2 += __shfl_xor(s2, off);
        s3 += __shfl_xor(s3, off);
        sa += __shfl_xor(sa, off);
        sq += __shfl_xor(sq, off);
        zc += __shfl_xor(zc, off);
        mx = fmaxf(mx, __shfl_xor(mx, off));
    }

    // abs in place; binary search bit-space for T = 409th largest |x|
    #pragma unroll
    for (int j = 0; j < 32; ++j) v[j] = fabsf(v[j]);

    unsigned lo = 0, hi = 0x7F800000u;   // invariant: cnt(hi) < TOPN, cnt(lo-1) >= TOPN
    while (lo < hi) {
        unsigned mid = (lo + hi) >> 1;
        float midf = __uint_as_float(mid);
        unsigned cnt = 0;
        #pragma unroll
        for (int j = 0; j < 32; ++j)
            cnt += (unsigned)__popcll(__ballot(v[j] > midf));
        if (cnt < TOPN) hi = mid; else lo = mid + 1;
    }
    const float T = __uint_as_float(lo);

    float cg = 0, sg = 0;
    #pragma unroll
    for (int j = 0; j < 32; ++j) {
        if (v[j] > T) { cg += 1.0f; sg += v[j]; }
    }
    #pragma unroll
    for (int off = 32; off >= 1; off >>= 1) { cg += __shfl_xor(cg, off); sg += __shfl_xor(sg, off); }

    if (lane == 0) {
        float top = sg + ((float)TOPN - cg) * T;
        float var_u = s2 * (1.0f/2047.0f);
        float stdv = sqrtf(var_u + 1e-8f);
        float st0 = zc * (1.0f/2048.0f);
        float st1 = var_u;
        float st2 = mx;
        float st3 = sqrtf(sq);
        float st4 = (s3 * (1.0f/2048.0f)) / (stdv*stdv*stdv);
        float st5 = top / (sa + 1e-8f);
        float* so = stats_out + (size_t)row * 6;
        so[0]=st0; so[1]=st1; so[2]=st2; so[3]=st3; so[4]=st4; so[5]=st5;
        // k predictor MLP (6->16->1) + sigmoid
        float stv[6] = {st0,st1,st2,st3,st4,st5};
        float o = bk2[0];
        #pragma unroll
        for (int i = 0; i < 16; ++i) {
            float h = bk1[i];
            #pragma unroll
            for (int f = 0; f < 6; ++f) h += stv[f] * Wk1[f*16 + i];
            o += fmaxf(h, 0.0f) * Wk2[i];
        }
        float kr = 1.0f / (1.0f + expf(-o));
        float kv = 1.0f + 3.0f * kr;
        kflags[row] = (kv < 2.0f ? 1u : 0u) | (kv < 3.0f ? 0x10000u : 0u);
    }
}

// ---------------- k-median: single-block reduce of per-row flags ----------------
__global__ __launch_bounds__(1024)
void kmed_kernel(const unsigned* __restrict__ kflags, int* __restrict__ counters)
{
    const int t = threadIdx.x;
    unsigned s = 0;
    for (int i = t; i < BB; i += 1024) s += kflags[i];
    #pragma unroll
    for (int off = 32; off >= 1; off >>= 1) s += __shfl_xor(s, off);
    __shared__ unsigned red[16];
    if ((t & 63) == 0) red[t >> 6] = s;
    __syncthreads();
    if (t == 0) {
        unsigned tot = 0;
        #pragma unroll
        for (int w = 0; w < 16; ++w) tot += red[w];
        counters[0] = (int)(tot & 0xFFFFu);
        counters[1] = (int)(tot >> 16);
    }
}

// ---------------- big GEMM: O = relu(A@B^T + bias), multi-phase split-bf16 ----------------
template<int NPH, bool SPLIT>
__global__ __launch_bounds__(256)
void gemm_tile(const u16* __restrict__ A0, const u16* __restrict__ B0,
               const u16* __restrict__ A1, const u16* __restrict__ B1,
               const u16* __restrict__ A2, const u16* __restrict__ B2,
               const float* __restrict__ bias,
               u16* __restrict__ Oh, u16* __restrict__ Ol,
               int kiters, int astride, int bstride)
{
    __shared__ u16 As[128*32];
    __shared__ u16 Bs[128*32];
    const int t = threadIdx.x;
    const int m0 = blockIdx.y * 128;
    const int n0 = blockIdx.x * 128;
    const int wid = t >> 6, lane = t & 63, l16 = lane & 15, q = lane >> 4;
    const int wm = (wid & 1) * 64, wn = (wid >> 1) * 64;

    f32x4 acc[4][4] = {};
    const u16* APh[3] = {A0, A1, A2};
    const u16* BPh[3] = {B0, B1, B2};

    for (int ph = 0; ph < NPH; ++ph) {
        const u16* A = APh[ph];
        const u16* B = BPh[ph];
        for (int it = 0; it < kiters; ++it) {
            const int k0 = it * 32;
            __syncthreads();
            #pragma unroll
            for (int s = 0; s < 2; ++s) {
                int seg = t + s * 256;
                int row = seg >> 2;
                int kq = (seg & 3) * 8;
                ld16_lds(A + (size_t)(m0 + row) * astride + k0 + kq, (void*)(As + seg * 8));
                ld16_lds(B + (size_t)(n0 + row) * bstride + k0 + kq, (void*)(Bs + seg * 8));
            }
            __syncthreads();
            bf16x8 af[4], bfr[4];
            #pragma unroll
            for (int i = 0; i < 4; ++i) af[i] = *(const bf16x8*)(As + (wm + 16*i + l16) * 32 + q * 8);
            #pragma unroll
            for (int j = 0; j < 4; ++j) bfr[j] = *(const bf16x8*)(Bs + (wn + 16*j + l16) * 32 + q * 8);
            #pragma unroll
            for (int i = 0; i < 4; ++i)
                #pragma unroll
                for (int j = 0; j < 4; ++j)
                    acc[i][j] = __builtin_amdgcn_mfma_f32_16x16x32_bf16(af[i], bfr[j], acc[i][j], 0, 0, 0);
        }
    }
    // epilogue: bias + relu + (split) bf16 store
    #pragma unroll
    for (int j = 0; j < 4; ++j) {
        int col = n0 + wn + 16*j + l16;
        float bv = bias[col];
        #pragma unroll
        for (int i = 0; i < 4; ++i) {
            #pragma unroll
            for (int r = 0; r < 4; ++r) {
                int row = m0 + wm + 16*i + q*4 + r;
                float vv = acc[i][j][r] + bv;
                vv = vv > 0.0f ? vv : 0.0f;
                u16 h = f2bf(vv);
                Oh[(size_t)row * HH + col] = h;
                if (SPLIT) Ol[(size_t)row * HH + col] = f2bf(vv - bf2f(h));
            }
        }
    }
}

// ---------------- thin GEMM: Out[m][16] = sum_ph A_ph @ B_ph^T (f32 out, no bias) ----------------
template<int NPH>
__global__ __launch_bounds__(256)
void thin_gemm(const u16* __restrict__ A0, const u16* __restrict__ B0,
               const u16* __restrict__ A1, const u16* __restrict__ B1,
               const u16* __restrict__ A2, const u16* __restrict__ B2,
               float* __restrict__ Out, int kiters, int astride, int bstride)
{
    const int t = threadIdx.x;
    const int wid = t >> 6, lane = t & 63, l16 = lane & 15, q = lane >> 4;
    const int m0 = (blockIdx.x * 4 + wid) * 16;
    f32x4 acc = {};
    const u16* APh[3] = {A0, A1, A2};
    const u16* BPh[3] = {B0, B1, B2};
    for (int ph = 0; ph < NPH; ++ph) {
        const u16* A = APh[ph];
        const u16* B = BPh[ph];
        for (int it = 0; it < kiters; ++it) {
            int k0 = it * 32;
            bf16x8 af = *(const bf16x8*)(A + (size_t)(m0 + l16) * astride + k0 + q*8);
            bf16x8 bfr = *(const bf16x8*)(B + (size_t)l16 * bstride + k0 + q*8);
            acc = __builtin_amdgcn_mfma_f32_16x16x32_bf16(af, bfr, acc, 0, 0, 0);
        }
    }
    #pragma unroll
    for (int r = 0; r < 4; ++r) {
        int row = m0 + q*4 + r;
        Out[(size_t)row * EE + l16] = acc[r];
    }
}

// ---------------- spec_scores -> ss columns of xh/xl ----------------
__global__ __launch_bounds__(256)
void ss_kernel(const float* __restrict__ sims, const float* __restrict__ spec,
               const float* __restrict__ bs2,
               u16* __restrict__ xh, u16* __restrict__ xl)
{
    int row = blockIdx.x * 256 + threadIdx.x;
    union { u16 a[8]; u16x8 vec; } H0, H1, L0, L1;
    #pragma unroll
    for (int e = 0; e < 16; ++e) {
        float sarg = sims[(size_t)row*EE + e] + spec[(size_t)row*EE + e] + bs2[e];
        float ssv = 1.0f / (1.0f + expf(-sarg));
        u16 h = f2bf(ssv);
        u16 lo = f2bf(ssv - bf2f(h));
        if (e < 8) { H0.a[e] = h; L0.a[e] = lo; } else { H1.a[e-8] = h; L1.a[e-8] = lo; }
    }
    u16x8 z = {0,0,0,0,0,0,0,0};
    u16* ph = xh + (size_t)row * KEXT + DD;
    u16* pl = xl + (size_t)row * KEXT + DD;
    *(u16x8*)(ph)      = H0.vec;
    *(u16x8*)(ph + 8)  = H1.vec;
    *(u16x8*)(ph + 16) = z;
    *(u16x8*)(ph + 24) = z;
    *(u16x8*)(pl)      = L0.vec;
    *(u16x8*)(pl + 8)  = L1.vec;
    *(u16x8*)(pl + 16) = z;
    *(u16x8*)(pl + 24) = z;
}

// ---------------- final: softmax, top-4, k from median counters, gates ----------------
__global__ __launch_bounds__(256)
void final_kernel(const float* __restrict__ logits, const float* __restrict__ br2,
                  const int* __restrict__ counters,
                  float* __restrict__ out_gates, float* __restrict__ out_idx,
                  float* __restrict__ out_probs)
{
    int row = blockIdx.x * 256 + threadIdx.x;
    float lg[16];
    float m = -1e30f;
    #pragma unroll
    for (int e = 0; e < 16; ++e) {
        lg[e] = logits[(size_t)row*EE + e] + br2[e];
        m = fmaxf(m, lg[e]);
    }
    float p[16], den = 0.0f;
    #pragma unroll
    for (int e = 0; e < 16; ++e) { p[e] = expf(lg[e] - m); den += p[e]; }
    float inv = 1.0f / den;
    #pragma unroll
    for (int e = 0; e < 16; ++e) { p[e] *= inv; out_probs[(size_t)row*EE + e] = p[e]; }

    float tv[4]; int ti[4];
    unsigned used = 0;
    #pragma unroll
    for (int s = 0; s < 4; ++s) {
        float best = -1e30f; int bi = 0;
        #pragma unroll
        for (int e = 0; e < 16; ++e) {
            if (!((used >> e) & 1u) && p[e] > best) { best = p[e]; bi = e; }
        }
        used |= 1u << bi;
        tv[s] = best; ti[s] = bi;
    }
    int c2 = counters[0], c3 = counters[1];
    int k = (c2 >= 8192) ? 1 : ((c3 >= 8192) ? 2 : 3);
    float g[4] = {0,0,0,0};
    float d2 = 0.0f;
    for (int s = 0; s < k; ++s) { g[s] = expf(tv[s] - tv[0]); d2 += g[s]; }
    float i2 = 1.0f / d2;
    #pragma unroll
    for (int s = 0; s < 4; ++s) {
        out_gates[(size_t)row*4 + s] = (s < k) ? g[s] * i2 : 0.0f;
        out_idx[(size_t)row*4 + s] = (float)ti[s];
    }
}

// ---------------- host launch ----------------
extern "C" void kernel_launch(void* const* d_in, const int* in_sizes, int n_in,
                              void* d_out, int out_size, void* d_ws, size_t ws_size,
                              hipStream_t stream) {
    const float* x   = (const float*)d_in[0];
    const float* pat = (const float*)d_in[1];
    const float* Ws1 = (const float*)d_in[2];
    const float* bs1 = (const float*)d_in[3];
    const float* Ws2 = (const float*)d_in[4];
    const float* bs2 = (const float*)d_in[5];
    const float* Wr1 = (const float*)d_in[6];
    const float* br1 = (const float*)d_in[7];
    const float* Wr2 = (const float*)d_in[8];
    const float* br2 = (const float*)d_in[9];
    const float* Wk1 = (const float*)d_in[10];
    const float* bk1 = (const float*)d_in[11];
    const float* Wk2 = (const float*)d_in[12];
    const float* bk2 = (const float*)d_in[13];

    char* ws = (char*)d_ws;
    size_t off = 0;
    auto alloc = [&](size_t bytes) { char* p = ws + off; off += (bytes + 255) & ~(size_t)255; return p; };
    u16* xh     = (u16*)alloc((size_t)BB * KEXT * 2);
    u16* xl     = (u16*)alloc((size_t)BB * KEXT * 2);
    u16* w1t    = (u16*)alloc((size_t)HH * KEXT * 2);
    u16* wr1h   = (u16*)alloc((size_t)HH * KEXT * 2);
    u16* wr1l   = (u16*)alloc((size_t)HH * KEXT * 2);
    u16* w2t1   = (u16*)alloc((size_t)EE * HH * 2);
    u16* wr2th  = (u16*)alloc((size_t)EE * HH * 2);
    u16* wr2tl  = (u16*)alloc((size_t)EE * HH * 2);
    u16* patTh  = (u16*)alloc((size_t)EE * DD * 2);
    u16* patTl  = (u16*)alloc((size_t)EE * DD * 2);
    u16* ha     = (u16*)alloc((size_t)BB * HH * 2);
    u16* hb     = (u16*)alloc((size_t)BB * HH * 2);
    float* sims   = (float*)alloc((size_t)BB * EE * 4);
    float* spec   = (float*)alloc((size_t)BB * EE * 4);
    float* logits = (float*)alloc((size_t)BB * EE * 4);
    unsigned* kflags = (unsigned*)alloc((size_t)BB * 4);
    int* cnt      = (int*)alloc(64);

    float* out        = (float*)d_out;
    float* out_gates  = out;
    float* out_idx    = out + (size_t)BB * 4;
    float* out_probs  = out + (size_t)BB * 8;
    float* out_stats  = out + (size_t)BB * 24;

    prep_w<<<(HH*KEXT + 255)/256, 256, 0, stream>>>(Ws1, Wr1, Ws2, Wr2, pat,
        w1t, wr1h, wr1l, w2t1, wr2th, wr2tl, patTh, patTl);

    stats_kernel<<<BB/4, 256, 0, stream>>>(x, Wk1, bk1, Wk2, bk2, out_stats, xh, xl, kflags);

    kmed_kernel<<<1, 1024, 0, stream>>>(kflags, cnt);

    // h1 = relu(x@Ws1 + bs1)  (plain bf16 is enough: feeds logits only via sigmoid'd spec)
    gemm_tile<1, false><<<dim3(8, 128), 256, 0, stream>>>(
        xh, w1t, nullptr, nullptr, nullptr, nullptr, bs1, ha, nullptr, 64, KEXT, KEXT);

    // sims = x @ patterns^T  (split 3-term)
    thin_gemm<3><<<BB/64, 256, 0, stream>>>(xh, patTh, xh, patTl, xl, patTh, sims, 64, KEXT, DD);

    // spec = h1 @ Ws2
    thin_gemm<1><<<BB/64, 256, 0, stream>>>(ha, w2t1, nullptr, nullptr, nullptr, nullptr, spec, 32, HH, HH);

    // ss = sigmoid(sims + spec + bs2) -> split bf16 into x_ext columns 2048..2079
    ss_kernel<<<BB/256, 256, 0, stream>>>(sims, spec, bs2, xh, xl);

    // h2 = relu(ri@Wr1 + br1), split 3-term, split-bf16 output
    gemm_tile<3, true><<<dim3(8, 128), 256, 0, stream>>>(
        xh, wr1h, xh, wr1l, xl, wr1h, br1, ha, hb, 65, KEXT, KEXT);

    // logits = h2 @ Wr2 (split 3-term)
    thin_gemm<3><<<BB/64, 256, 0, stream>>>(ha, wr2th, ha, wr2tl, hb, wr2th, logits, 32, HH, HH);

    final_kernel<<<BB/256, 256, 0, stream>>>(logits, br2, cnt, out_gates, out_idx, out_probs);
}